// Round 4
// baseline (554.915 us; speedup 1.0000x reference)
//
#include <hip/hip_runtime.h>
#include <cstdint>
#include <cstddef>

// N=50000 nodes, E=500000 edges, EMB=64, PRED_IN=276.
// Padded-K bf16 MFMA layout (K=288 = 9*32):
//   pk   0.. 63 : q_emb     (k 0..63)
//   pk  64..127 : edge_attr (k 138..201)
//   pk 128..207 : h_e[src]  (k 64..137) + 6 pad
//   pk 208..287 : h_e[dst]  (k 202..275) + 6 pad
// h_e stored bf16 [N][80]: x(64) topic(2) f1(2) f2(2) r1(2) r2(2) pad(6).
//
// Round-6 (R3 post-mortem: BW pinned at 2.3-2.4 TB/s across structures and
// occupancies -> per-CU outstanding-miss limit, not occupancy/LDS). Change:
// depth-3 per-wave pipeline: 8-wave blocks, he ring of 3 LDS buffers,
// TWO 15-op batches in flight (s_waitcnt vmcnt(30)), idx prefetch depth 5.
// Tail waits degrade 30->15->0. k_w1t folded into k_detect (one less launch).

typedef __bf16 bf16x8 __attribute__((ext_vector_type(8)));
typedef float f32x4 __attribute__((ext_vector_type(4)));

__device__ __forceinline__ unsigned int f2bf1(float f) {   // RNE fp32->bf16
    unsigned int u = __float_as_uint(f);
    return (u + 0x7fffu + ((u >> 16) & 1u)) >> 16;
}
__device__ __forceinline__ unsigned int pk2(float a, float b) {
    return f2bf1(a) | (f2bf1(b) << 16);
}
__device__ __forceinline__ bf16x8 cvt8v(float4 a, float4 b) {
    bf16x8 r;
    r[0] = (__bf16)a.x; r[1] = (__bf16)a.y; r[2] = (__bf16)a.z; r[3] = (__bf16)a.w;
    r[4] = (__bf16)b.x; r[5] = (__bf16)b.y; r[6] = (__bf16)b.z; r[7] = (__bf16)b.w;
    return r;
}

#define GL16(gp, lp)                                                        \
    __builtin_amdgcn_global_load_lds(                                       \
        (const __attribute__((address_space(1))) void*)(gp),                \
        (__attribute__((address_space(3))) void*)(lp), 16, 0, 0)

// ---------------------------------------------------------------------------
// Prep
// ---------------------------------------------------------------------------

// blocks [0, gE): detect int64 layout; blocks [gE, gE+72): build W1T table.
// W1T linear-LDS layout: ushort index i = ((ct*9 + ks)*64 + l)*8 + j
// holds W1[pk-mapped k][col] for col = ct*16 + (l&15), pk = ks*32 + (l>>4)*8 + j.
__global__ void k_detect(const int* __restrict__ idx, int E, int* __restrict__ flag,
                         int gE, const float* __restrict__ W1,
                         unsigned short* __restrict__ W1T) {
    if ((int)blockIdx.x >= gE) {
        int i = (blockIdx.x - gE) * blockDim.x + threadIdx.x;
        if (i >= 64 * 288) return;
        int j = i & 7;
        int l = (i >> 3) & 63;
        int t36 = i >> 9;              // ct*9 + ks
        int ks = t36 % 9, ct = t36 / 9;
        int col = ct * 16 + (l & 15);
        int pk = ks * 32 + (l >> 4) * 8 + j;
        int k = 0; bool valid = true;
        if (pk < 64)       { k = pk; }
        else if (pk < 128) { k = 138 + (pk - 64); }
        else if (pk < 208) { int jj = pk - 128; k = 64 + jj;  valid = jj < 74; }
        else               { int jj = pk - 208; k = 202 + jj; valid = jj < 74; }
        float v = valid ? W1[k * 64 + col] : 0.f;
        W1T[i] = (unsigned short)f2bf1(v);
        return;
    }
    int e = blockIdx.x * blockDim.x + threadIdx.x;
    bool nz = (e < E) && (idx[2 * e + 1] != 0);
    unsigned long long m = __ballot(nz);
    if (m != 0ull && (threadIdx.x & 63) == 0) atomicOr(flag, 1);
}

__global__ void k_convert(const int* __restrict__ idx, int E, const int* __restrict__ flag,
                          int* __restrict__ src_i, int* __restrict__ dst_i,
                          int* __restrict__ cnt_dst, int* __restrict__ cnt_src,
                          unsigned short* __restrict__ pos_f, unsigned short* __restrict__ pos_r) {
    int e = blockIdx.x * blockDim.x + threadIdx.x;
    if (e >= E) return;
    int s, d;
    if (*flag) { s = idx[e];     d = idx[E + e]; }
    else       { s = idx[2 * e]; d = idx[2 * E + 2 * e]; }
    src_i[e] = s; dst_i[e] = d;
    pos_f[e] = (unsigned short)atomicAdd(&cnt_dst[d], 1);
    pos_r[e] = (unsigned short)atomicAdd(&cnt_src[s], 1);
}

__global__ void k_scan(const int* __restrict__ cnt_dst, const int* __restrict__ cnt_src,
                       int* __restrict__ off_f, int* __restrict__ off_r, int N) {
    const int* cnt = (blockIdx.x == 0) ? cnt_dst : cnt_src;
    int* off       = (blockIdx.x == 0) ? off_f   : off_r;
    const int t = threadIdx.x;                 // 1024 threads
    const int C = (N + 1023) / 1024;
    int lo = t * C, hi = lo + C; if (hi > N) hi = N; if (lo > N) lo = N;
    int sum = 0;
    for (int i = lo; i < hi; ++i) sum += cnt[i];
    __shared__ int wsum[16];
    int lane = t & 63, wv = t >> 6;
    int v = sum;
    for (int ofs = 1; ofs < 64; ofs <<= 1) {
        int u = __shfl_up(v, ofs);
        if (lane >= ofs) v += u;
    }
    if (lane == 63) wsum[wv] = v;
    __syncthreads();
    if (wv == 0) {
        int x = (lane < 16) ? wsum[lane] : 0;
        for (int ofs = 1; ofs < 16; ofs <<= 1) {
            int u = __shfl_up(x, ofs);
            if (lane >= ofs) x += u;
        }
        if (lane < 16) wsum[lane] = x;
    }
    __syncthreads();
    int base = (wv > 0 ? wsum[wv - 1] : 0) + (v - sum);
    for (int i = lo; i < hi; ++i) { off[i] = base; base += cnt[i]; }
}

__global__ void k_fill(const int* __restrict__ src_i, const int* __restrict__ dst_i,
                       const unsigned short* __restrict__ pos_f, const unsigned short* __restrict__ pos_r,
                       const int* __restrict__ off_f, const int* __restrict__ off_r,
                       int* __restrict__ csr_f, int* __restrict__ csr_r, int E) {
    int e = blockIdx.x * blockDim.x + threadIdx.x;
    if (e >= E) return;
    int s = src_i[e], d = dst_i[e];
    csr_f[off_f[d] + pos_f[e]] = s;
    csr_r[off_r[s] + pos_r[e]] = d;
}

__global__ void k_round(const int* __restrict__ off_f, const int* __restrict__ csr_f,
                        const int* __restrict__ off_r, const int* __restrict__ csr_r,
                        const float* __restrict__ hf_in,
                        const float* __restrict__ hr_in,
                        float* __restrict__ f_out, float* __restrict__ r_out,
                        int N, int E) {
    int gid = blockIdx.x * blockDim.x + threadIdx.x;
    if (gid >= 2 * N) return;
    const bool rev = gid >= N;
    const int n = rev ? gid - N : gid;
    const int* __restrict__ off = rev ? off_r : off_f;
    const int* __restrict__ csr = rev ? csr_r : csr_f;
    const float2* __restrict__ h = (const float2*)(rev ? hr_in : hf_in);
    float2* __restrict__ o = (float2*)(rev ? r_out : f_out);
    int b = off[n], e = (n + 1 < N) ? off[n + 1] : E;
    float sx = 0.f, sy = 0.f;
    for (int j = b; j < e; ++j) { float2 t = h[csr[j]]; sx += t.x; sy += t.y; }
    float inv = 1.0f / (float)max(e - b, 1);
    o[n] = make_float2(sx * inv, sy * inv);
}

__global__ void k_build(const float* __restrict__ x, const float* __restrict__ topic,
                        const float* __restrict__ nte,
                        const float* __restrict__ f1, const float* __restrict__ f2,
                        const float* __restrict__ r1, const float* __restrict__ r2,
                        unsigned short* __restrict__ he, int N) {
    int n = blockIdx.x * blockDim.x + threadIdx.x;
    if (n >= N) return;
    const float4* xr = (const float4*)(x + (size_t)n * 64);
    float4 v[16];
    bool allz = true;
#pragma unroll
    for (int i = 0; i < 16; ++i) {
        v[i] = xr[i];
        allz = allz && (v[i].x == 0.f && v[i].y == 0.f && v[i].z == 0.f && v[i].w == 0.f);
    }
    const float4* nr = (const float4*)nte;
    unsigned int row[40];
#pragma unroll
    for (int i = 0; i < 16; ++i) {
        float4 s = allz ? nr[i] : v[i];
        row[2 * i]     = pk2(s.x, s.y);
        row[2 * i + 1] = pk2(s.z, s.w);
    }
    row[32] = pk2(topic[2 * n], topic[2 * n + 1]);
    row[33] = pk2(f1[2 * n], f1[2 * n + 1]);
    row[34] = pk2(f2[2 * n], f2[2 * n + 1]);
    row[35] = pk2(r1[2 * n], r1[2 * n + 1]);
    row[36] = pk2(r2[2 * n], r2[2 * n + 1]);
    row[37] = 0u; row[38] = 0u; row[39] = 0u;
    uint4* dst = (uint4*)(he + (size_t)n * 80);
#pragma unroll
    for (int i = 0; i < 10; ++i) dst[i] = ((const uint4*)row)[i];
}

// ---------------------------------------------------------------------------
// MFMA edge-MLP, depth-3 async pipeline.
// 512 threads = 8 waves/block, 16 edges (1 M-tile) per wave per iteration.
// LDS 159,744 B: [W1T 36,864][wave w: ring of 3 he-buffers, 5,120 B each]
//   -> 1 block/CU, 8 waves/CU = 2 waves/SIMD.
// he buffer: chunk-plane layout, plane p (0..19) at p*256 + edge*16:
//   planes 0..9 = he[src] chunks, planes 10..19 = he[dst] chunks.
// Steady loop per wave (no barriers):
//   issue batch k = { 8 q/ea reg loads (T+2NW), 5 global_load_lds
//   (T+2NW -> ring[(k+2)%3], addrs from idx loaded 3 batches ago),
//   2 idx loads (T+5NW) }  == 15 VMEM ops
//   s_waitcnt vmcnt(30)   // batch k-2 (tile T's data) complete; k-1,k in flight
//   compute tile T; tail degrades vmcnt 30 -> 15 -> 0.
// ---------------------------------------------------------------------------

__launch_bounds__(512, 2)
__global__ void k_gemm(const float* __restrict__ q_emb,
                       const float* __restrict__ edge_attr,
                       const unsigned short* __restrict__ he,
                       const unsigned short* __restrict__ W1Tg,
                       const int* __restrict__ src_i, const int* __restrict__ dst_i,
                       const float* __restrict__ b1, const float* __restrict__ W2,
                       const float* __restrict__ b2, float* __restrict__ out, int E)
{
    __shared__ __align__(64) char smem[159744];
    const int tid = threadIdx.x;
    const int w = tid >> 6, l = tid & 63, c = l & 15, q = l >> 4;
    const int NW = gridDim.x * 8;
    const int gw = blockIdx.x * 8 + w;
    const int ntiles = E / 16;          // E % 16 == 0

    // W1T -> LDS (36 KB linear copy; 36 x 1KB DMA, spread over 8 waves)
    for (int j = w; j < 36; j += 8) {
        GL16((const char*)W1Tg + j * 1024 + l * 16, smem + j * 1024);
    }

    char* bufb = smem + 36864 + w * 15360;   // ring slot r: bufb + r*5120

#define EIDX(t) ((((t) < ntiles) ? (t) : (ntiles - 1)) * 16 + c)

    int T = gw;
    // ---- prologue: stage he(T)->slot0, he(T+NW)->slot1; q/ea(T),(T+NW) regs;
    //      idx prefetch for T+2NW, T+3NW, T+4NW. __syncthreads drains all.
    {
        int e0 = EIDX(T);        int s0 = src_i[e0], d0 = dst_i[e0];
        int e1 = EIDX(T + NW);   int s1 = src_i[e1], d1 = dst_i[e1];
#pragma unroll
        for (int j = 0; j < 5; ++j) {
            int ch = j * 4 + q;
            int nsel0 = ch < 10 ? s0 : d0; int ck = ch < 10 ? ch : ch - 10;
            int nsel1 = ch < 10 ? s1 : d1;
            GL16((const char*)he + (size_t)nsel0 * 160 + ck * 16, bufb + j * 1024);
            GL16((const char*)he + (size_t)nsel1 * 160 + ck * 16, bufb + 5120 + j * 1024);
        }
    }
    const float* qr0 = q_emb     + (size_t)EIDX(T) * 64 + q * 8;
    const float* ar0 = edge_attr + (size_t)EIDX(T) * 64 + q * 8;
    float4 qc0 = *(const float4*)qr0,        qc1 = *(const float4*)(qr0 + 4);
    float4 qc2 = *(const float4*)(qr0 + 32), qc3 = *(const float4*)(qr0 + 36);
    float4 ec0 = *(const float4*)ar0,        ec1 = *(const float4*)(ar0 + 4);
    float4 ec2 = *(const float4*)(ar0 + 32), ec3 = *(const float4*)(ar0 + 36);
    const float* qr1 = q_emb     + (size_t)EIDX(T + NW) * 64 + q * 8;
    const float* ar1 = edge_attr + (size_t)EIDX(T + NW) * 64 + q * 8;
    float4 q10 = *(const float4*)qr1,        q11 = *(const float4*)(qr1 + 4);
    float4 q12 = *(const float4*)(qr1 + 32), q13 = *(const float4*)(qr1 + 36);
    float4 e10 = *(const float4*)ar1,        e11 = *(const float4*)(ar1 + 4);
    float4 e12 = *(const float4*)(ar1 + 32), e13 = *(const float4*)(ar1 + 36);
    int si2, di2, si3, di3, si4, di4;
    { int e = EIDX(T + 2 * NW); si2 = src_i[e]; di2 = dst_i[e]; }
    { int e = EIDX(T + 3 * NW); si3 = src_i[e]; di3 = dst_i[e]; }
    { int e = EIDX(T + 4 * NW); si4 = src_i[e]; di4 = dst_i[e]; }

    float b1v[4], w2v[4];
#pragma unroll
    for (int ct = 0; ct < 4; ++ct) { b1v[ct] = b1[ct * 16 + c]; w2v[ct] = W2[ct * 16 + c]; }
    const float bb = b2[0];
    __syncthreads();   // drains W1T + prologue DMA/loads; W1T visible to all

    int rc = 0;        // compute ring slot; staging slot = (rc+2)%3
    while (T < ntiles) {
        const bool more1 = (T + NW) < ntiles;
        const bool more2 = (T + 2 * NW) < ntiles;
        float4 q20, q21, q22, q23, e20, e21, e22, e23;
        int sin = si3, din = di3;   // defaults for rotation at tail

        if (more2) {
            const int Tp = T + 2 * NW;
            const float* qr = q_emb     + (size_t)(Tp * 16 + c) * 64 + q * 8;
            const float* ar = edge_attr + (size_t)(Tp * 16 + c) * 64 + q * 8;
            q20 = *(const float4*)qr;        q21 = *(const float4*)(qr + 4);
            q22 = *(const float4*)(qr + 32); q23 = *(const float4*)(qr + 36);
            e20 = *(const float4*)ar;        e21 = *(const float4*)(ar + 4);
            e22 = *(const float4*)(ar + 32); e23 = *(const float4*)(ar + 36);
            int rs = rc + 2; rs = rs >= 3 ? rs - 3 : rs;
            char* sbuf = bufb + rs * 5120;
#pragma unroll
            for (int j = 0; j < 5; ++j) {
                int ch = j * 4 + q;
                int node = ch < 10 ? si2 : di2;
                int ck = ch < 10 ? ch : ch - 10;
                GL16((const char*)he + (size_t)node * 160 + ck * 16, sbuf + j * 1024);
            }
            int ep = EIDX(T + 5 * NW);
            sin = src_i[ep]; din = dst_i[ep];
            asm volatile("s_waitcnt vmcnt(30)" ::: "memory");
        } else if (more1) {
            q20 = qc0; q21 = qc1; q22 = qc2; q23 = qc3;
            e20 = ec0; e21 = ec1; e22 = ec2; e23 = ec3;
            asm volatile("s_waitcnt vmcnt(15)" ::: "memory");
        } else {
            q20 = qc0; q21 = qc1; q22 = qc2; q23 = qc3;
            e20 = ec0; e21 = ec1; e22 = ec2; e23 = ec3;
            asm volatile("s_waitcnt vmcnt(0)" ::: "memory");
        }
        __builtin_amdgcn_sched_barrier(0);

        // ---- compute tile T from ring slot rc ----
        char* cbuf = bufb + rc * 5120;
        f32x4 acc0 = {}, acc1 = {}, acc2 = {}, acc3 = {};
        const char* wbase = smem + (size_t)l * 16;
#define BF(ct, ks) (*(const bf16x8*)(wbase + (ct) * 9216 + (ks) * 1024))
#define HEF(pl) (*(const bf16x8*)(cbuf + (pl) * 256 + c * 16))
#define KST(ks, A)                                                                 \
        {                                                                          \
            bf16x8 a_ = (A);                                                       \
            acc0 = __builtin_amdgcn_mfma_f32_16x16x32_bf16(a_, BF(0, ks), acc0, 0, 0, 0); \
            acc1 = __builtin_amdgcn_mfma_f32_16x16x32_bf16(a_, BF(1, ks), acc1, 0, 0, 0); \
            acc2 = __builtin_amdgcn_mfma_f32_16x16x32_bf16(a_, BF(2, ks), acc2, 0, 0, 0); \
            acc3 = __builtin_amdgcn_mfma_f32_16x16x32_bf16(a_, BF(3, ks), acc3, 0, 0, 0); \
        }
        KST(0, cvt8v(qc0, qc1))
        KST(1, cvt8v(qc2, qc3))
        KST(2, cvt8v(ec0, ec1))
        KST(3, cvt8v(ec2, ec3))
        KST(4, HEF(q))            // hs chunks q
        KST(5, HEF(q + 4))        // hs chunks q+4
        KST(6, HEF(q + 8))        // q<2: hs 8,9 ; q>=2: hd 0,1 (planes contiguous)
        KST(7, HEF(q + 12))       // hd chunks 2..5
        KST(8, HEF(q + 16))       // hd chunks 6..9
#undef KST
#undef HEF
#undef BF

        float pr[4];
#pragma unroll
        for (int r = 0; r < 4; ++r) {
            float h0 = fmaxf(acc0[r] + b1v[0], 0.f);
            float h1 = fmaxf(acc1[r] + b1v[1], 0.f);
            float h2 = fmaxf(acc2[r] + b1v[2], 0.f);
            float h3 = fmaxf(acc3[r] + b1v[3], 0.f);
            float p = fmaf(h0, w2v[0], fmaf(h1, w2v[1], fmaf(h2, w2v[2], h3 * w2v[3])));
            p += __shfl_xor(p, 1);
            p += __shfl_xor(p, 2);
            p += __shfl_xor(p, 4);
            p += __shfl_xor(p, 8);
            pr[r] = p;
        }
        if (c == 0) {
            *(float4*)&out[T * 16 + q * 4] =
                make_float4(pr[0] + bb, pr[1] + bb, pr[2] + bb, pr[3] + bb);
        }

        // rotate register pipelines
        qc0 = q10; qc1 = q11; qc2 = q12; qc3 = q13;
        ec0 = e10; ec1 = e11; ec2 = e12; ec3 = e13;
        q10 = q20; q11 = q21; q12 = q22; q13 = q23;
        e10 = e20; e11 = e21; e12 = e22; e13 = e23;
        si2 = si3; di2 = di3; si3 = si4; di3 = di4; si4 = sin; di4 = din;
        rc = rc == 2 ? 0 : rc + 1;
        T += NW;
    }
#undef EIDX
}

// ---------------------------------------------------------------------------
// Launch
// ---------------------------------------------------------------------------

extern "C" void kernel_launch(void* const* d_in, const int* in_sizes, int n_in,
                              void* d_out, int out_size, void* d_ws, size_t ws_size,
                              hipStream_t stream)
{
    const float* x         = (const float*)d_in[0];
    const int*   eidx      = (const int*)  d_in[1];
    const float* edge_attr = (const float*)d_in[2];
    const float* topic     = (const float*)d_in[3];
    const float* q_emb     = (const float*)d_in[4];
    const float* nte       = (const float*)d_in[5];
    const float* W1        = (const float*)d_in[6];
    const float* b1        = (const float*)d_in[7];
    const float* W2        = (const float*)d_in[8];
    const float* b2        = (const float*)d_in[9];
    float* out = (float*)d_out;

    const int E = out_size;             // 500000
    const int N = in_sizes[0] / 64;     // 50000

    char* ws = (char*)d_ws;
    int* flag  = (int*)ws;
    int* src_i = (int*)(ws + 16);
    int* dst_i = src_i + E;
    int* off_f = dst_i + E;
    int* off_r = off_f + N;
    float* fblk = (float*)(off_r + N);
    float* f1 = fblk;
    float* f2 = fblk + 2 * (size_t)N;
    float* r1 = fblk + 4 * (size_t)N;
    float* r2 = fblk + 6 * (size_t)N;
    int* cnt_dst = (int*)f1;            // dead before f1 is written
    int* cnt_src = cnt_dst + N;
    char* heblk = (char*)(fblk + 8 * (size_t)N);
    unsigned short* pos_f = (unsigned short*)heblk;          // dead before he is written
    unsigned short* pos_r = pos_f + E;
    int* csr_f = (int*)(pos_r + E);
    int* csr_r = csr_f + E;
    unsigned short* he = (unsigned short*)heblk;
    size_t he_bytes = (size_t)N * 160;
    size_t trans_bytes = (size_t)E * 12;
    size_t heblk_bytes = he_bytes > trans_bytes ? he_bytes : trans_bytes;
    unsigned short* W1T = (unsigned short*)(heblk + heblk_bytes);

    size_t needed = 16 + (size_t)8 * E + (size_t)8 * N + (size_t)32 * N + heblk_bytes + 64 * 288 * 2;
    if (ws_size < needed) return;

    hipMemsetAsync(flag, 0, 16, stream);
    hipMemsetAsync(cnt_dst, 0, (size_t)8 * N, stream);   // both cnt arrays

    const int gE = (E + 255) / 256;
    const int gN = (N + 255) / 256;
    const int gN2 = (2 * N + 255) / 256;
    const int gW = (64 * 288 + 255) / 256;   // 72 blocks of W1T work

    k_detect <<<gE + gW, 256, 0, stream>>>(eidx, E, flag, gE, W1, W1T);
    k_convert<<<gE, 256, 0, stream>>>(eidx, E, flag, src_i, dst_i,
                                      cnt_dst, cnt_src, pos_f, pos_r);
    k_scan   <<<2, 1024, 0, stream>>>(cnt_dst, cnt_src, off_f, off_r, N);
    k_fill   <<<gE, 256, 0, stream>>>(src_i, dst_i, pos_f, pos_r, off_f, off_r,
                                      csr_f, csr_r, E);
    k_round  <<<gN2, 256, 0, stream>>>(off_f, csr_f, off_r, csr_r, topic, topic, f1, r1, N, E);
    k_round  <<<gN2, 256, 0, stream>>>(off_f, csr_f, off_r, csr_r, f1, r1, f2, r2, N, E);
    k_build  <<<gN, 256, 0, stream>>>(x, topic, nte, f1, f2, r1, r2, he, N);

    k_gemm<<<256, 512, 0, stream>>>(q_emb, edge_attr, he, W1T,
                                    src_i, dst_i, b1, W2, b2, out, E);
}